// Round 1
// baseline (397.417 us; speedup 1.0000x reference)
//
#include <hip/hip_runtime.h>
#include <stdint.h>

typedef __bf16 bf16x8 __attribute__((ext_vector_type(8)));
typedef float f32x4 __attribute__((ext_vector_type(4)));
typedef unsigned short ushort_t;

#define N_OUT 11008
#define K_DIM 4096
#define M_DIM 512
#define BM 256
#define BN 64
#define BK 32
#define NK_TILES 128  /* K_DIM / BK */
#define LDB 40        /* padded lds_b row, ushorts (32 + 8) */

__constant__ float c_nf4[16] = {
    -1.0f, -0.6961928009986877f, -0.5250730514526367f, -0.39491748809814453f,
    -0.28444138169288635f, -0.18477343022823334f, -0.09105003625154495f, 0.0f,
    0.07958029955625534f, 0.16093020141124725f, 0.24611230194568634f,
    0.33791524171829224f, 0.44070982933044434f, 0.5626170039176941f,
    0.7229568362236023f, 1.0f};

// round-half-up fp32 -> bf16, pack two into u32
__device__ __forceinline__ uint32_t pkbf(float lo, float hi) {
  uint32_t ul = __builtin_bit_cast(uint32_t, lo);
  uint32_t uh = __builtin_bit_cast(uint32_t, hi);
  return ((ul + 0x8000u) >> 16) | ((uh + 0x8000u) & 0xffff0000u);
}

__device__ __forceinline__ void async16(const void* g, void* l) {
  __builtin_amdgcn_global_load_lds(
      (const __attribute__((address_space(1))) void*)g,
      (__attribute__((address_space(3))) void*)l, 16, 0, 0);
}

__device__ __forceinline__ bf16x8 ldfrag(const ushort_t* p) {
  uint4 r = *reinterpret_cast<const uint4*>(p);
  return __builtin_bit_cast(bf16x8, r);
}

// ---------------- prep kernel 1: x fp32 -> bf16 ----------------
__global__ void k_cvt_x(const float* __restrict__ x, ushort_t* __restrict__ xbf) {
  int i = blockIdx.x * blockDim.x + threadIdx.x;  // 262144 threads * 8 floats
  const float4* xp = reinterpret_cast<const float4*>(x) + (size_t)i * 2;
  float4 v0 = xp[0], v1 = xp[1];
  uint4 o;
  o.x = pkbf(v0.x, v0.y);
  o.y = pkbf(v0.z, v0.w);
  o.z = pkbf(v1.x, v1.y);
  o.w = pkbf(v1.z, v1.w);
  reinterpret_cast<uint4*>(xbf)[i] = o;
}

// ---------------- prep kernel 2: xa = 2*(x @ lora_A), padded [512,32] bf16 ----
__global__ void k_xa(const float* __restrict__ x, const float* __restrict__ lA,
                     ushort_t* __restrict__ xap) {
  int m = blockIdx.x;
  int t = threadIdx.x;
  int r = t & 15, part = t >> 4;  // 16 ranks x 16 k-partitions
  const float* xr = x + (size_t)m * K_DIM + part * 256;
  const float* ar = lA + (size_t)(part * 256) * 16 + r;
  float acc = 0.f;
#pragma unroll 8
  for (int k = 0; k < 256; ++k) acc += xr[k] * ar[(size_t)k * 16];
  __shared__ float red[16][17];
  red[part][r] = acc;
  __syncthreads();
  if (t < 32) {
    float v = 0.f;
    if (t < 16) {
      for (int p = 0; p < 16; ++p) v += red[p][t];
      v *= 2.0f;  // SCALING folded in here
    }
    uint32_t u = __builtin_bit_cast(uint32_t, v);
    xap[(size_t)m * 32 + t] = (ushort_t)((u + 0x8000u) >> 16);
  }
}

// ---------------- prep kernel 3: Bt = lora_B^T, padded [11008,32] bf16 -------
__global__ void k_bt(const float* __restrict__ lB, ushort_t* __restrict__ btp) {
  int o = blockIdx.x * blockDim.x + threadIdx.x;  // 43*256 = 11008 exact
  uint32_t p[8];
#pragma unroll
  for (int j = 0; j < 8; ++j)
    p[j] = pkbf(lB[(size_t)(2 * j) * N_OUT + o], lB[(size_t)(2 * j + 1) * N_OUT + o]);
  uint4* dst = reinterpret_cast<uint4*>(btp + (size_t)o * 32);
  dst[0] = make_uint4(p[0], p[1], p[2], p[3]);
  dst[1] = make_uint4(p[4], p[5], p[6], p[7]);
  dst[2] = make_uint4(0u, 0u, 0u, 0u);
  dst[3] = make_uint4(0u, 0u, 0u, 0u);
}

// ---------------- main fused GEMM -------------------------------------------
// BM=256 x BN=64 tile, BK=32, 4 waves each 64x64 (4x4 of 16x16x32 bf16 MFMA).
// K-loop has 129 tiles: 128 dequant tiles + 1 LoRA tile (K-extension trick).
__launch_bounds__(256, 2)
__global__ void k_main(const ushort_t* __restrict__ xbf, const int* __restrict__ wi,
                       const float* __restrict__ sc, const ushort_t* __restrict__ xap,
                       const ushort_t* __restrict__ btp, const float* __restrict__ bias,
                       float* __restrict__ out) {
  __shared__ __align__(16) ushort_t lds_a[BM * BK];   // 16 KB, [m][k], unpadded (DMA dest)
  __shared__ __align__(16) ushort_t lds_b[BN * LDB];  // 5 KB, [n][k], +8 pad
  __shared__ float lutf[16];                          // 16 banks -> conflict-free

  const int t = threadIdx.x;
  const int lane = t & 63;
  const int w = t >> 6;
  const int o0 = blockIdx.x * BN;
  const int m0 = blockIdx.y * BM;

  if (t < 16) lutf[t] = c_nf4[t];

  // ---- A staging: 16 KB / (256 thr * 16 B) = 4 rounds; wave-chunked for DMA
  const int kb = (lane & 3) * 8;  // bf16 elem offset within 32-elem row
  const ushort_t* ga[4];
#pragma unroll
  for (int j = 0; j < 4; ++j) {
    int arow = (j * 4 + w) * 16 + (lane >> 2);
    ga[j] = xbf + (size_t)(m0 + arow) * K_DIM + kb;
  }

  // ---- B staging: 64 rows x 32 elems; thread -> (row=t>>2, 8 elems)
  const int ro = t >> 2;
  const int q4 = (t & 3) * 8;
  const int* gb = wi + (size_t)(o0 + ro) * K_DIM + q4;
  const float* gs = sc + (size_t)(o0 + ro) * 64;  // one scale / row / k-tile
  ushort_t* lb_dst = lds_b + ro * LDB + q4;

  // ---- fragment read bases
  const ushort_t* af_base = lds_a + (w * 64 + (lane & 15)) * BK + (lane >> 4) * 8;
  const ushort_t* bf_base = lds_b + (lane & 15) * LDB + (lane >> 4) * 8;

  f32x4 acc[4][4];
#pragma unroll
  for (int mi = 0; mi < 4; ++mi)
#pragma unroll
    for (int ni = 0; ni < 4; ++ni) acc[mi][ni] = (f32x4){0.f, 0.f, 0.f, 0.f};

  // prologue prefetch of tile 0 indices + scale
  int4 i0 = ((const int4*)gb)[0];
  int4 i1 = ((const int4*)gb)[1];
  float s = gs[0];
  gb += BK;

  for (int kt = 0; kt < NK_TILES + 1; ++kt) {
    __syncthreads();  // previous tile's frag reads done (also covers lut init)
    if (kt < NK_TILES) {
#pragma unroll
      for (int j = 0; j < 4; ++j) {
        async16(ga[j], lds_a + (j * 4 + w) * 512 + lane * 8);
        ga[j] += BK;
      }
      // dequant prefetched 8 indices -> 8 bf16, one ds_write_b128
      uint32_t p0 = pkbf(lutf[i0.x] * s, lutf[i0.y] * s);
      uint32_t p1 = pkbf(lutf[i0.z] * s, lutf[i0.w] * s);
      uint32_t p2 = pkbf(lutf[i1.x] * s, lutf[i1.y] * s);
      uint32_t p3 = pkbf(lutf[i1.z] * s, lutf[i1.w] * s);
      *reinterpret_cast<uint4*>(lb_dst) = make_uint4(p0, p1, p2, p3);
      if (kt + 1 < NK_TILES) {  // prefetch next tile's indices + scale
        i0 = ((const int4*)gb)[0];
        i1 = ((const int4*)gb)[1];
        s = gs[(kt + 1) >> 1];
        gb += BK;
      }
    } else {
      // LoRA K-extension tile: A from xa_pad, B from Bt_pad (already bf16)
#pragma unroll
      for (int j = 0; j < 4; ++j) {
        int arow = (j * 4 + w) * 16 + (lane >> 2);
        async16(xap + (size_t)(m0 + arow) * 32 + kb,
                lds_a + (j * 4 + w) * 512 + lane * 8);
      }
      uint4 bv = *reinterpret_cast<const uint4*>(btp + (size_t)(o0 + ro) * 32 + q4);
      *reinterpret_cast<uint4*>(lb_dst) = bv;
    }
    __syncthreads();  // staging visible (compiler drains vmcnt for DMA)

    bf16x8 av[4], bv[4];
#pragma unroll
    for (int mi = 0; mi < 4; ++mi) av[mi] = ldfrag(af_base + mi * 16 * BK);
#pragma unroll
    for (int ni = 0; ni < 4; ++ni) bv[ni] = ldfrag(bf_base + ni * 16 * LDB);
#pragma unroll
    for (int mi = 0; mi < 4; ++mi)
#pragma unroll
      for (int ni = 0; ni < 4; ++ni)
        acc[mi][ni] =
            __builtin_amdgcn_mfma_f32_16x16x32_bf16(av[mi], bv[ni], acc[mi][ni], 0, 0, 0);
  }

  // epilogue: + bias, store. C/D layout: col=lane&15, row=(lane>>4)*4+i
  const int cl = lane & 15, rg = (lane >> 4) * 4;
#pragma unroll
  for (int ni = 0; ni < 4; ++ni) {
    int col = o0 + ni * 16 + cl;
    float bvs = bias[col];
#pragma unroll
    for (int mi = 0; mi < 4; ++mi) {
      int row0 = m0 + w * 64 + mi * 16 + rg;
      float* op = out + (size_t)row0 * N_OUT + col;
#pragma unroll
      for (int i = 0; i < 4; ++i) op[(size_t)i * N_OUT] = acc[mi][ni][i] + bvs;
    }
  }
}

extern "C" void kernel_launch(void* const* d_in, const int* in_sizes, int n_in,
                              void* d_out, int out_size, void* d_ws, size_t ws_size,
                              hipStream_t stream) {
  const float* x = (const float*)d_in[0];
  const int* wi = (const int*)d_in[1];
  const float* sc = (const float*)d_in[2];
  const float* lA = (const float*)d_in[3];
  const float* lB = (const float*)d_in[4];
  const float* bias = (const float*)d_in[5];
  float* out = (float*)d_out;

  char* wsb = (char*)d_ws;
  ushort_t* xbf = (ushort_t*)wsb;                            // 4 MB: 512*4096 bf16
  ushort_t* xap = (ushort_t*)(wsb + (4u << 20));             // 32 KB: 512*32 bf16
  ushort_t* btp = (ushort_t*)(wsb + (4u << 20) + (32u << 10));  // 704 KB: 11008*32 bf16

  k_cvt_x<<<1024, 256, 0, stream>>>(x, xbf);
  k_xa<<<M_DIM, 256, 0, stream>>>(x, lA, xap);
  k_bt<<<43, 256, 0, stream>>>(lB, btp);
  dim3 grid(N_OUT / BN, M_DIM / BM);
  k_main<<<grid, 256, 0, stream>>>(xbf, wi, sc, xap, btp, bias, out);
}

// Round 2
// 357.387 us; speedup vs baseline: 1.1120x; 1.1120x over previous
//
#include <hip/hip_runtime.h>
#include <stdint.h>

typedef __bf16 bf16x8 __attribute__((ext_vector_type(8)));
typedef float f32x4 __attribute__((ext_vector_type(4)));
typedef unsigned short ushort_t;

#define N_OUT 11008
#define K_DIM 4096
#define M_DIM 512
#define BM 256
#define BN 64
#define BK 64
#define KHALF 2048
#define NT 32 /* KHALF / BK */

__constant__ float c_nf4[16] = {
    -1.0f, -0.6961928009986877f, -0.5250730514526367f, -0.39491748809814453f,
    -0.28444138169288635f, -0.18477343022823334f, -0.09105003625154495f, 0.0f,
    0.07958029955625534f, 0.16093020141124725f, 0.24611230194568634f,
    0.33791524171829224f, 0.44070982933044434f, 0.5626170039176941f,
    0.7229568362236023f, 1.0f};

// round-half-up fp32 -> bf16, pack two into u32
__device__ __forceinline__ uint32_t pkbf(float lo, float hi) {
  uint32_t ul = __builtin_bit_cast(uint32_t, lo);
  uint32_t uh = __builtin_bit_cast(uint32_t, hi);
  return ((ul + 0x8000u) >> 16) | ((uh + 0x8000u) & 0xffff0000u);
}

__device__ __forceinline__ void async16(const void* g, void* l) {
  __builtin_amdgcn_global_load_lds(
      (const __attribute__((address_space(1))) void*)g,
      (__attribute__((address_space(3))) void*)l, 16, 0, 0);
}

__device__ __forceinline__ bf16x8 ldfrag(const ushort_t* p) {
  uint4 r = *reinterpret_cast<const uint4*>(p);
  return __builtin_bit_cast(bf16x8, r);
}

__device__ __forceinline__ uint32_t dq2(int a, int b, float s, const float2* lut) {
  float2 l = lut[a | (b << 4)];
  return pkbf(l.x * s, l.y * s);
}

// =============== fused prep: cvt+swizzle | x@A | B^T | bias-init =============
// grid: [0,1024) cvt, [1024,1536) xa, [1536,1579) bt, [1579,7083) bias-init
__global__ void k_prep(const float* __restrict__ x, const float* __restrict__ lA,
                       const float* __restrict__ lB, const float* __restrict__ bias,
                       ushort_t* __restrict__ xbf, ushort_t* __restrict__ xap,
                       ushort_t* __restrict__ btp, float* __restrict__ out) {
  const int b = blockIdx.x, t = threadIdx.x;
  if (b < 1024) {
    // x fp32 -> bf16 with XOR chunk swizzle inside each 64-elem k-window:
    // stored chunk position cp holds original chunk cp ^ (m&7)
    int oc = b * 256 + t;          // 16B output chunk id (8 bf16)
    int m = oc >> 9;               // 512 chunks per row
    int cr = oc & 511;
    int win = cr >> 3, cp = cr & 7;
    int c = cp ^ (m & 7);
    const float4* s4 = (const float4*)(x + (size_t)m * K_DIM + win * 64 + c * 8);
    float4 v0 = s4[0], v1 = s4[1];
    uint4 o;
    o.x = pkbf(v0.x, v0.y);
    o.y = pkbf(v0.z, v0.w);
    o.z = pkbf(v1.x, v1.y);
    o.w = pkbf(v1.z, v1.w);
    ((uint4*)xbf)[oc] = o;
  } else if (b < 1536) {
    // xa = 2*(x @ lora_A) for one row m, padded [512,32] bf16
    __shared__ float red[256 * 17];
    int m = b - 1024;
    int ks = t * 16;
    alignas(16) float xs[16];
    const f32x4* xv = (const f32x4*)(x + (size_t)m * K_DIM + ks);
    ((f32x4*)xs)[0] = xv[0];
    ((f32x4*)xs)[1] = xv[1];
    ((f32x4*)xs)[2] = xv[2];
    ((f32x4*)xs)[3] = xv[3];
    f32x4 ac0 = 0.f, ac1 = 0.f, ac2 = 0.f, ac3 = 0.f;
#pragma unroll
    for (int kk = 0; kk < 16; ++kk) {
      float xk = xs[kk];
      const f32x4* l4 = (const f32x4*)(lA + (size_t)(ks + kk) * 16);
      ac0 += xk * l4[0];
      ac1 += xk * l4[1];
      ac2 += xk * l4[2];
      ac3 += xk * l4[3];
    }
#pragma unroll
    for (int r = 0; r < 4; ++r) {
      red[t * 17 + r] = ac0[r];
      red[t * 17 + 4 + r] = ac1[r];
      red[t * 17 + 8 + r] = ac2[r];
      red[t * 17 + 12 + r] = ac3[r];
    }
    __syncthreads();
#pragma unroll
    for (int s = 128; s >= 16; s >>= 1) {
      if (t < s)
        for (int r = 0; r < 16; ++r) red[t * 17 + r] += red[(t + s) * 17 + r];
      __syncthreads();
    }
    if (t < 32) {
      float v = 0.f;
      if (t < 16) {
        for (int p = 0; p < 16; ++p) v += red[p * 17 + t];
        v *= 2.0f;  // SCALING
      }
      uint32_t u = __builtin_bit_cast(uint32_t, v);
      xap[(size_t)m * 32 + t] = (ushort_t)((u + 0x8000u) >> 16);
    }
  } else if (b < 1579) {
    // Bt = lora_B^T, padded [11008,32] bf16
    int o = (b - 1536) * 256 + t;
    uint32_t p[8];
#pragma unroll
    for (int j = 0; j < 8; ++j)
      p[j] = pkbf(lB[(size_t)(2 * j) * N_OUT + o], lB[(size_t)(2 * j + 1) * N_OUT + o]);
    uint4* dst = reinterpret_cast<uint4*>(btp + (size_t)o * 32);
    dst[0] = make_uint4(p[0], p[1], p[2], p[3]);
    dst[1] = make_uint4(p[4], p[5], p[6], p[7]);
    dst[2] = make_uint4(0u, 0u, 0u, 0u);
    dst[3] = make_uint4(0u, 0u, 0u, 0u);
  } else {
    // out = broadcast bias (split-K blocks atomically add on top)
    int i = (b - 1579) * 256 + t;  // float4 id, 1,409,024 total
    int col4 = i % 2752;           // 11008/4
    ((float4*)out)[i] = ((const float4*)bias)[col4];
  }
}

// =============== main fused GEMM (split-K=2, atomic epilogue) ===============
// BM=256 x BN=64, BK=64, 4 waves; wave w owns rows [w*64, w*64+64), acc 4x4.
// A: global_load_lds (16B) from pre-swizzled xbf -> conflict-free frag reads.
// B: int4 register prefetch -> pair-LUT dequant -> ds_write_b128.
__launch_bounds__(256, 3)
__global__ void k_main(const ushort_t* __restrict__ xbf, const int* __restrict__ wi,
                       const float* __restrict__ sc, const ushort_t* __restrict__ xap,
                       const ushort_t* __restrict__ btp, float* __restrict__ out) {
  __shared__ __align__(16) ushort_t lds_a[BM * BK];  // 32 KB, [row][c'], swizzled
  __shared__ __align__(16) ushort_t lds_b[BN * 72];  // 9 KB, +8 pad
  __shared__ float2 lutp[256];                       // pair LUT, 2 KB

  const int t = threadIdx.x;
  const int lane = t & 63;
  const int w = t >> 6;
  const int o0 = blockIdx.x * BN;
  const int m0 = blockIdx.y * BM;
  const int kh = blockIdx.z;
  const int k0 = kh * KHALF;

  lutp[t] = make_float2(c_nf4[t & 15], c_nf4[t >> 4]);

  // B staging: thread -> (row=t>>2, 16 ints at (t&3)*16)
  const int brow = t >> 2, bq = t & 3;
  const int* gb = wi + (size_t)(o0 + brow) * K_DIM + k0 + bq * 16;
  const float* gs = sc + (size_t)(o0 + brow) * 64 + kh * 32;  // 1 scale/row/tile
  ushort_t* lb = lds_b + brow * 72 + bq * 16;

  // A DMA: wave w stages its own rows [w*64, w*64+64); 8 instrs x 1KB
  const ushort_t* ga =
      xbf + (size_t)(m0 + w * 64 + (lane >> 3)) * K_DIM + k0 + (lane & 7) * 8;
  ushort_t* la_dst = lds_a + w * 4096 + lane * 8;

  f32x4 acc[4][4];
#pragma unroll
  for (int mi = 0; mi < 4; ++mi)
#pragma unroll
    for (int ni = 0; ni < 4; ++ni) acc[mi][ni] = (f32x4){0.f, 0.f, 0.f, 0.f};

  // prologue: prefetch tile 0 indices + scale
  int4 bi0 = ((const int4*)gb)[0], bi1 = ((const int4*)gb)[1];
  int4 bi2 = ((const int4*)gb)[2], bi3 = ((const int4*)gb)[3];
  float s = gs[0];
  gb += BK;
  uint4 braw;

  const ushort_t* afb = lds_a + (w * 64 + (lane & 15)) * BK;
  const int q = lane >> 4;
  const ushort_t* bfb = lds_b + (lane & 15) * 72 + q * 8;

#pragma unroll 1
  for (int kt = 0; kt < NT; ++kt) {
    __syncthreads();  // prev tile's frag reads done (covers LUT init at kt=0)
    // dequant 16 idx -> 16 bf16 via pair LUT, 2x ds_write_b128
    uint4 w0, w1;
    w0.x = dq2(bi0.x, bi0.y, s, lutp);
    w0.y = dq2(bi0.z, bi0.w, s, lutp);
    w0.z = dq2(bi1.x, bi1.y, s, lutp);
    w0.w = dq2(bi1.z, bi1.w, s, lutp);
    w1.x = dq2(bi2.x, bi2.y, s, lutp);
    w1.y = dq2(bi2.z, bi2.w, s, lutp);
    w1.z = dq2(bi3.x, bi3.y, s, lutp);
    w1.w = dq2(bi3.z, bi3.w, s, lutp);
    *reinterpret_cast<uint4*>(lb) = w0;
    *reinterpret_cast<uint4*>(lb + 8) = w1;
    // A DMA for this tile (own wave's rows only)
#pragma unroll
    for (int j = 0; j < 8; ++j)
      async16(ga + (size_t)j * 8 * K_DIM + kt * BK, la_dst + j * 512);
    __syncthreads();  // drains DMA + makes lds_b visible
    // prefetch next tile (in flight during MFMA phase)
    if (kt + 1 < NT) {
      bi0 = ((const int4*)gb)[0];
      bi1 = ((const int4*)gb)[1];
      bi2 = ((const int4*)gb)[2];
      bi3 = ((const int4*)gb)[3];
      s = gs[kt + 1];
      gb += BK;
    } else if (kh == 1) {
      braw = *reinterpret_cast<const uint4*>(btp + (size_t)(o0 + brow) * 32 + bq * 8);
    }
    // fragments + 32 MFMA
#pragma unroll
    for (int kc = 0; kc < 2; ++kc) {
      const int cpr = ((kc * 4 + q) ^ (lane & 7)) * 8;  // un-swizzle
      bf16x8 av[4], bv[4];
#pragma unroll
      for (int mi = 0; mi < 4; ++mi) av[mi] = ldfrag(afb + mi * 16 * BK + cpr);
#pragma unroll
      for (int ni = 0; ni < 4; ++ni) bv[ni] = ldfrag(bfb + ni * 16 * 72 + kc * 32);
#pragma unroll
      for (int mi = 0; mi < 4; ++mi)
#pragma unroll
        for (int ni = 0; ni < 4; ++ni)
          acc[mi][ni] = __builtin_amdgcn_mfma_f32_16x16x32_bf16(av[mi], bv[ni],
                                                                acc[mi][ni], 0, 0, 0);
    }
  }

  // LoRA K-extension tail (kh==1 only): BK=32, A from xap, B from btp
  if (kh == 1) {
    __syncthreads();
    *reinterpret_cast<uint4*>(lds_b + brow * 72 + bq * 8) = braw;
#pragma unroll
    for (int j = 0; j < 4; ++j)
      async16(xap + (size_t)(m0 + w * 64 + j * 16 + (lane >> 2)) * 32 + (lane & 3) * 8,
              lds_a + w * 2048 + j * 512 + lane * 8);
    __syncthreads();
    bf16x8 av[4], bv[4];
#pragma unroll
    for (int mi = 0; mi < 4; ++mi)
      av[mi] = ldfrag(lds_a + w * 2048 + (mi * 16 + (lane & 15)) * 32 + q * 8);
#pragma unroll
    for (int ni = 0; ni < 4; ++ni)
      bv[ni] = ldfrag(lds_b + (ni * 16 + (lane & 15)) * 72 + q * 8);
#pragma unroll
    for (int mi = 0; mi < 4; ++mi)
#pragma unroll
      for (int ni = 0; ni < 4; ++ni)
        acc[mi][ni] = __builtin_amdgcn_mfma_f32_16x16x32_bf16(av[mi], bv[ni],
                                                              acc[mi][ni], 0, 0, 0);
  }

  // epilogue: atomic add onto bias-pre-initialized out
  const int cl = lane & 15, rg = q * 4;
#pragma unroll
  for (int ni = 0; ni < 4; ++ni) {
    int col = o0 + ni * 16 + cl;
#pragma unroll
    for (int mi = 0; mi < 4; ++mi) {
      int row0 = m0 + w * 64 + mi * 16 + rg;
      float* op = out + (size_t)row0 * N_OUT + col;
#pragma unroll
      for (int i = 0; i < 4; ++i) atomicAdd(op + (size_t)i * N_OUT, acc[mi][ni][i]);
    }
  }
}

extern "C" void kernel_launch(void* const* d_in, const int* in_sizes, int n_in,
                              void* d_out, int out_size, void* d_ws, size_t ws_size,
                              hipStream_t stream) {
  const float* x = (const float*)d_in[0];
  const int* wi = (const int*)d_in[1];
  const float* sc = (const float*)d_in[2];
  const float* lA = (const float*)d_in[3];
  const float* lB = (const float*)d_in[4];
  const float* bias = (const float*)d_in[5];
  float* out = (float*)d_out;

  char* wsb = (char*)d_ws;
  ushort_t* xbf = (ushort_t*)wsb;                               // 4 MB
  ushort_t* xap = (ushort_t*)(wsb + (4u << 20));                // 32 KB
  ushort_t* btp = (ushort_t*)(wsb + (4u << 20) + (32u << 10));  // 704 KB

  k_prep<<<7083, 256, 0, stream>>>(x, lA, lB, bias, xbf, xap, btp, out);
  dim3 grid(N_OUT / BN, M_DIM / BM, 2);
  k_main<<<grid, 256, 0, stream>>>(xbf, wi, sc, xap, btp, out);
}